// Round 1
// baseline (911.246 us; speedup 1.0000x reference)
//
#include <hip/hip_runtime.h>
#include <math.h>

#define DEVFN __device__ __forceinline__

// Problem constants
constexpr int T_ = 32;
constexpr int N_ = 64;            // B*T
constexpr int HW = 128;
constexpr int C1IN = 1928;        // z rows (1 sca + 1927 emb)
constexpr int C1 = 964;
constexpr int P1W = 99;           // pooled width after cnn1
constexpr int C2 = 482;
constexpr int C3 = 241;
constexpr int C4 = 100;

DEVFN float sigm(float x) { return 1.0f / (1.0f + __expf(-x)); }

// ---------------------------------------------------------------------------
// K1: conv_con (4x4 s2) + relu + maxpool 2x2 + fc_con  ->  sca[n][200]
__global__ void k_sca(const float* __restrict__ replay, const float* __restrict__ wc,
                      const float* __restrict__ bc, const float* __restrict__ fcw,
                      const float* __restrict__ fcb, float* __restrict__ sca) {
    const int n = blockIdx.x;                                 // 0..63
    const float* x = replay + (size_t)n * 8 * HW * HW;        // channel 0
    __shared__ __align__(16) float y[961];
    __shared__ float wcs[16];
    if (threadIdx.x < 16) wcs[threadIdx.x] = wc[threadIdx.x];
    const float bcv = bc[0];
    __syncthreads();
    for (int idx = threadIdx.x; idx < 961; idx += blockDim.x) {
        const int i = idx / 31, j = idx % 31;
        float m = 0.0f;
        #pragma unroll
        for (int di = 0; di < 2; ++di)
        #pragma unroll
        for (int dj = 0; dj < 2; ++dj) {
            const int ci = 2 * i + di, cj = 2 * j + dj;       // conv output coords
            const int h0 = 2 * ci, w0 = 2 * cj;
            float acc = bcv;
            #pragma unroll
            for (int p = 0; p < 4; ++p)
            #pragma unroll
            for (int q = 0; q < 4; ++q)
                acc += x[(h0 + p) * HW + (w0 + q)] * wcs[p * 4 + q];
            m = fmaxf(m, fmaxf(acc, 0.0f));
        }
        y[idx] = m;
    }
    __syncthreads();
    for (int o = threadIdx.x; o < 200; o += blockDim.x) {
        float acc = fcb[o];
        const float* wr = fcw + (size_t)o * 961;
        for (int m = 0; m < 961; ++m) acc += y[m] * wr[m];
        sca[n * 200 + o] = acc;
    }
}

// ---------------------------------------------------------------------------
// K2a: Wsum[oc][kw] = sum_ic W1[oc][ic][kw]
__global__ void k_wsum(const float* __restrict__ w1, float* __restrict__ wsum) {
    const int oc = blockIdx.x;                                 // 964 blocks, 64 thr
    const float* wr = w1 + (size_t)oc * C1IN * 2;
    float s0 = 0.f, s1 = 0.f;
    for (int ic = threadIdx.x; ic < C1IN; ic += 64) {
        s0 += wr[ic * 2 + 0];
        s1 += wr[ic * 2 + 1];
    }
    #pragma unroll
    for (int off = 32; off > 0; off >>= 1) {
        s0 += __shfl_down(s0, off);
        s1 += __shfl_down(s1, off);
    }
    if (threadIdx.x == 0) { wsum[oc * 2] = s0; wsum[oc * 2 + 1] = s1; }
}

// K2b: SA[n][oc][kw] = sum over active emb rows of W1[oc][ic][kw]
__global__ void k_sa(const float* __restrict__ replay, const float* __restrict__ w1,
                     float* __restrict__ sa) {
    const int n = blockIdx.y;
    const int oc = blockIdx.x * blockDim.x + threadIdx.x;
    if (oc >= C1) return;
    const int chs[5]    = {1, 3, 5, 6, 7};
    const int scales[5] = {4, 2, 5, 2, 1914};
    const int offs[5]   = {0, 4, 6, 11, 13};
    float s0 = 0.f, s1 = 0.f;
    #pragma unroll
    for (int k = 0; k < 5; ++k) {
        int v = (int)replay[((size_t)n * 8 + chs[k]) * HW * HW];   // [b,t,ch,0,0]
        if (v > scales[k]) v = 0;
        if (v >= 1 && v <= scales[k] - 1) {
            const int ic = 1 + offs[k] + v;
            s0 += w1[((size_t)oc * C1IN + ic) * 2 + 0];
            s1 += w1[((size_t)oc * C1IN + ic) * 2 + 1];
        }
    }
    sa[(n * C1 + oc) * 2 + 0] = s0;
    sa[(n * C1 + oc) * 2 + 1] = s1;
}

// ---------------------------------------------------------------------------
// K3: cnn1 via exact low-rank decomposition + relu + pool(1,2) -> p1[n][964][99]
template <int OCT>
__global__ void k_cnn1(const float* __restrict__ sca, const float* __restrict__ emb,
                       const float* __restrict__ w1, const float* __restrict__ b1,
                       const float* __restrict__ wsum, const float* __restrict__ sa,
                       float* __restrict__ p1) {
    const int n = blockIdx.x;
    const int ocBase = blockIdx.y * OCT;
    __shared__ float ev[200], sv[200], dv[200];
    __shared__ float oscal[OCT][7];
    for (int i = threadIdx.x; i < 200; i += blockDim.x) {
        const float e0 = emb[i], e1 = emb[200 + i];
        ev[i] = e0;
        dv[i] = e1 - e0;
        sv[i] = sca[n * 200 + i] - e0;
    }
    for (int i = threadIdx.x; i < OCT * 7; i += blockDim.x) {
        const int ocl = i / 7, f = i % 7;
        const int oc = ocBase + ocl;
        float v = 0.f;
        if (oc < C1) {
            switch (f) {
                case 0: v = wsum[oc * 2 + 0]; break;
                case 1: v = wsum[oc * 2 + 1]; break;
                case 2: v = b1[oc]; break;
                case 3: v = w1[(size_t)oc * C1IN * 2 + 0]; break;
                case 4: v = w1[(size_t)oc * C1IN * 2 + 1]; break;
                case 5: v = sa[(n * C1 + oc) * 2 + 0]; break;
                case 6: v = sa[(n * C1 + oc) * 2 + 1]; break;
            }
        }
        oscal[ocl][f] = v;
    }
    __syncthreads();
    for (int item = threadIdx.x; item < OCT * P1W; item += blockDim.x) {
        const int ocl = item / P1W, u = item % P1W;
        const int oc = ocBase + ocl;
        if (oc >= C1) continue;
        const float ws0 = oscal[ocl][0], ws1 = oscal[ocl][1], bb = oscal[ocl][2];
        const float a0 = oscal[ocl][3], a1 = oscal[ocl][4];
        const float s0 = oscal[ocl][5], s1 = oscal[ocl][6];
        float r = -INFINITY;
        #pragma unroll
        for (int dw = 0; dw < 2; ++dw) {
            const int ww = 2 * u + dw;
            const float o = bb + ws0 * ev[ww] + ws1 * ev[ww + 1]
                               + a0 * sv[ww] + a1 * sv[ww + 1]
                               + s0 * dv[ww] + s1 * dv[ww + 1];
            r = fmaxf(r, o);
        }
        p1[((size_t)n * C1 + oc) * P1W + u] = fmaxf(r, 0.0f);
    }
}

// ---------------------------------------------------------------------------
// Generic conv (1x2 kernel over width) + bias + relu [+ pool(1,2)]
// in: [N][IC][WIN], w: [OC][IC][2], out: [N][OC][NOUT]
template <int IC, int OC, int WIN, bool POOL>
__global__ __launch_bounds__(256) void k_conv(const float* __restrict__ in,
                                              const float* __restrict__ w,
                                              const float* __restrict__ bias,
                                              float* __restrict__ out) {
    constexpr int WOUT = WIN - 1;
    constexpr int NOUT = POOL ? (WOUT / 2) : WOUT;
    constexpr int OCT = 32;
    constexpr int KT = 32;
    constexpr int MAXU = (NOUT + 15) / 16;
    constexpr int PSTRIDE = (WIN % 2) ? (WIN + 1) : WIN;
    constexpr int WSTRIDE = 2 * KT + 2;   // 66: breaks 8-way bank conflict

    __shared__ __align__(16) float pt[KT * PSTRIDE];
    __shared__ __align__(16) float wt[OCT * WSTRIDE];

    const int n = blockIdx.x;
    const int ocBase = blockIdx.y * OCT;
    const int tx = threadIdx.x;
    const int ocg = tx >> 4;              // 0..15
    const int ol = tx & 15;               // 0..15
    const int oc0 = ocBase + 2 * ocg;
    const int oc1 = oc0 + 1;

    float acc[2][2][MAXU];
    #pragma unroll
    for (int a = 0; a < 2; ++a)
        #pragma unroll
        for (int q = 0; q < 2; ++q)
            #pragma unroll
            for (int r = 0; r < MAXU; ++r) acc[a][q][r] = 0.f;

    const float* inn = in + (size_t)n * IC * WIN;

    for (int icb = 0; icb < IC; icb += KT) {
        const int kt = min(KT, IC - icb);
        __syncthreads();
        for (int i = tx; i < KT * WIN; i += 256) {
            const int r = i / WIN, c = i - r * WIN;
            pt[r * PSTRIDE + c] = (r < kt) ? inn[icb * WIN + i] : 0.0f;
        }
        for (int i = tx; i < OCT * 2 * KT; i += 256) {
            const int r = i / (2 * KT), c = i - r * (2 * KT);
            const int oc = ocBase + r;
            const int ic = icb + (c >> 1);
            float v = 0.f;
            if (oc < OC && ic < IC) v = w[((size_t)oc * IC + ic) * 2 + (c & 1)];
            wt[r * WSTRIDE + c] = v;
        }
        __syncthreads();
        #pragma unroll 4
        for (int ic = 0; ic < KT; ++ic) {
            const float2 w0 = *(const float2*)&wt[(2 * ocg) * WSTRIDE + 2 * ic];
            const float2 w1v = *(const float2*)&wt[(2 * ocg + 1) * WSTRIDE + 2 * ic];
            #pragma unroll
            for (int r = 0; r < MAXU; ++r) {
                const int u = ol + 16 * r;
                if (u < NOUT) {
                    if (POOL) {
                        const int wb = 2 * u;
                        const float2 pp = *(const float2*)&pt[ic * PSTRIDE + wb];
                        const float p2v = pt[ic * PSTRIDE + wb + 2];
                        acc[0][0][r] += w0.x * pp.x + w0.y * pp.y;
                        acc[1][0][r] += w1v.x * pp.x + w1v.y * pp.y;
                        acc[0][1][r] += w0.x * pp.y + w0.y * p2v;
                        acc[1][1][r] += w1v.x * pp.y + w1v.y * p2v;
                    } else {
                        const float p0 = pt[ic * PSTRIDE + u];
                        const float p1v = pt[ic * PSTRIDE + u + 1];
                        acc[0][0][r] += w0.x * p0 + w0.y * p1v;
                        acc[1][0][r] += w1v.x * p0 + w1v.y * p1v;
                    }
                }
            }
        }
    }

    const float b0 = (oc0 < OC) ? bias[oc0] : 0.f;
    const float b1v = (oc1 < OC) ? bias[oc1] : 0.f;
    float* outn = out + (size_t)n * OC * NOUT;
    #pragma unroll
    for (int r = 0; r < MAXU; ++r) {
        const int u = ol + 16 * r;
        if (u < NOUT) {
            if (POOL) {
                if (oc0 < OC) outn[oc0 * NOUT + u] = fmaxf(fmaxf(acc[0][0][r], acc[0][1][r]) + b0, 0.f);
                if (oc1 < OC) outn[oc1 * NOUT + u] = fmaxf(fmaxf(acc[1][0][r], acc[1][1][r]) + b1v, 0.f);
            } else {
                if (oc0 < OC) outn[oc0 * NOUT + u] = fmaxf(acc[0][0][r] + b0, 0.f);
                if (oc1 < OC) outn[oc1 * NOUT + u] = fmaxf(acc[1][0][r] + b1v, 0.f);
            }
        }
    }
}

// ---------------------------------------------------------------------------
// fc_cnn: seq[n][100] = z4[n][2300] @ W.T + b
__global__ void k_fc_cnn(const float* __restrict__ z4, const float* __restrict__ w,
                         const float* __restrict__ b, float* __restrict__ seq) {
    const int n = blockIdx.x;
    __shared__ __align__(16) float zb[2300];
    for (int i = threadIdx.x; i < 2300; i += blockDim.x) zb[i] = z4[(size_t)n * 2300 + i];
    __syncthreads();
    if (threadIdx.x < 100) {
        const int o = threadIdx.x;
        const float4* wr = (const float4*)(w + (size_t)o * 2300);
        const float4* zb4 = (const float4*)zb;
        float4 a = {0.f, 0.f, 0.f, 0.f};
        for (int m = 0; m < 575; ++m) {
            const float4 wv = wr[m];
            const float4 zv = zb4[m];
            a.x += wv.x * zv.x; a.y += wv.y * zv.y;
            a.z += wv.z * zv.z; a.w += wv.w * zv.w;
        }
        seq[n * 100 + o] = b[o] + a.x + a.y + a.z + a.w;
    }
}

// xg[n][400] = seq[n] @ W_ih.T + b_ih + b_hh  (hoisted out of the recurrence)
__global__ void k_xg(const float* __restrict__ seq, const float* __restrict__ wih,
                     const float* __restrict__ bih, const float* __restrict__ bhh,
                     float* __restrict__ xg) {
    const int n = blockIdx.x;
    __shared__ __align__(16) float s[100];
    if (threadIdx.x < 100) s[threadIdx.x] = seq[n * 100 + threadIdx.x];
    __syncthreads();
    const int g = threadIdx.x;
    if (g < 400) {
        const float4* wr = (const float4*)(wih + (size_t)g * 100);
        const float4* s4 = (const float4*)s;
        float4 a = {0.f, 0.f, 0.f, 0.f};
        #pragma unroll
        for (int m = 0; m < 25; ++m) {
            const float4 wv = wr[m];
            const float4 sv = s4[m];
            a.x += wv.x * sv.x; a.y += wv.y * sv.y;
            a.z += wv.z * sv.z; a.w += wv.w * sv.w;
        }
        xg[n * 400 + g] = bih[g] + bhh[g] + a.x + a.y + a.z + a.w;
    }
}

__global__ void k_whhT(const float* __restrict__ whh, float* __restrict__ whhT) {
    const int i = blockIdx.x * blockDim.x + threadIdx.x;
    if (i < 40000) {
        const int g = i / 100, m = i - g * 100;
        whhT[m * 400 + g] = whh[i];
    }
}

// LSTM recurrence (both batches in one block) + final fc_out
__global__ __launch_bounds__(832) void k_lstm(const float* __restrict__ xg,
                                              const float* __restrict__ whhT,
                                              const float* __restrict__ fw,
                                              const float* __restrict__ fb,
                                              float* __restrict__ outp) {
    __shared__ float h[2][100], c[2][100], g[2][400];
    const int tx = threadIdx.x;
    for (int i = tx; i < 200; i += blockDim.x) { h[i / 100][i % 100] = 0.f; c[i / 100][i % 100] = 0.f; }
    __syncthreads();
    const int b = tx / 400, gi = tx - b * 400;   // valid for tx < 800
    for (int t = 0; t < T_; ++t) {
        if (tx < 800) {
            const int n = b * T_ + t;
            float acc = xg[n * 400 + gi];
            #pragma unroll 4
            for (int m = 0; m < 100; ++m)
                acc += h[b][m] * whhT[m * 400 + gi];
            g[b][gi] = acc;
        }
        __syncthreads();
        if (tx < 200) {
            const int bb = tx / 100, j = tx - bb * 100;
            const float iv = g[bb][j], fv = g[bb][100 + j];
            const float gv = g[bb][200 + j], ov = g[bb][300 + j];
            const float cn = sigm(fv) * c[bb][j] + sigm(iv) * tanhf(gv);
            c[bb][j] = cn;
            h[bb][j] = sigm(ov) * tanhf(cn);
        }
        __syncthreads();
    }
    if (tx < 4) {
        const int bb = tx >> 1, k = tx & 1;
        float acc = fb[k];
        for (int j = 0; j < 100; ++j) acc += h[bb][j] * fw[k * 100 + j];
        outp[bb * 2 + k] = acc;
    }
}

// ---------------------------------------------------------------------------
extern "C" void kernel_launch(void* const* d_in, const int* in_sizes, int n_in,
                              void* d_out, int out_size, void* d_ws, size_t ws_size,
                              hipStream_t stream) {
    (void)in_sizes; (void)n_in; (void)out_size; (void)ws_size;
    const float* replay = (const float*)d_in[0];
    const float* emb    = (const float*)d_in[1];
    const float* ccw    = (const float*)d_in[2];
    const float* ccb    = (const float*)d_in[3];
    const float* fcw    = (const float*)d_in[4];
    const float* fcb    = (const float*)d_in[5];
    const float* w1     = (const float*)d_in[6];
    const float* b1     = (const float*)d_in[7];
    const float* w2     = (const float*)d_in[8];
    const float* b2     = (const float*)d_in[9];
    const float* w3     = (const float*)d_in[10];
    const float* b3     = (const float*)d_in[11];
    const float* w4     = (const float*)d_in[12];
    const float* b4     = (const float*)d_in[13];
    const float* fcnw   = (const float*)d_in[14];
    const float* fcnb   = (const float*)d_in[15];
    const float* wih    = (const float*)d_in[16];
    const float* whh    = (const float*)d_in[17];
    const float* bih    = (const float*)d_in[18];
    const float* bhh    = (const float*)d_in[19];
    const float* fow    = (const float*)d_in[20];
    const float* fob    = (const float*)d_in[21];

    float* ws   = (float*)d_ws;
    float* sca  = ws + 0;          // 64*200          = 12800
    float* wsum = ws + 12800;      // 964*2           = 1928
    float* sa   = ws + 14728;      // 64*964*2        = 123392
    float* p1   = ws + 138120;     // 64*964*99       = 6107904
    float* p2   = ws + 6246024;    // 64*482*49       = 1511552
    float* p3   = ws + 7757576;    // 64*241*24       = 370176
    float* z4   = ws + 8127752;    // 64*100*23       = 147200
    float* seq  = ws + 8274952;    // 64*100          = 6400
    float* xg   = ws + 8281352;    // 64*400          = 25600
    float* whhT = ws + 8306952;    // 100*400         = 40000  (total 8346952 fl = 33.4 MB)
    float* outp = (float*)d_out;

    k_sca<<<64, 256, 0, stream>>>(replay, ccw, ccb, fcw, fcb, sca);
    k_wsum<<<964, 64, 0, stream>>>(w1, wsum);
    k_sa<<<dim3(4, 64), 256, 0, stream>>>(replay, w1, sa);
    k_whhT<<<157, 256, 0, stream>>>(whh, whhT);
    k_cnn1<16><<<dim3(64, 61), 256, 0, stream>>>(sca, emb, w1, b1, wsum, sa, p1);
    k_conv<964, 482, 99, true><<<dim3(64, 16), 256, 0, stream>>>(p1, w2, b2, p2);
    k_conv<482, 241, 49, true><<<dim3(64, 8), 256, 0, stream>>>(p2, w3, b3, p3);
    k_conv<241, 100, 24, false><<<dim3(64, 4), 256, 0, stream>>>(p3, w4, b4, z4);
    k_fc_cnn<<<64, 128, 0, stream>>>(z4, fcnw, fcnb, seq);
    k_xg<<<64, 512, 0, stream>>>(seq, wih, bih, bhh, xg);
    k_lstm<<<1, 832, 0, stream>>>(xg, whhT, fow, fob, outp);
}

// Round 2
// 420.258 us; speedup vs baseline: 2.1683x; 2.1683x over previous
//
#include <hip/hip_runtime.h>
#include <math.h>

#define DEVFN __device__ __forceinline__

typedef __bf16 bf16x8 __attribute__((ext_vector_type(8)));
typedef float f32x4 __attribute__((ext_vector_type(4)));

// Problem constants
constexpr int T_ = 32;
constexpr int HW = 128;
constexpr int C1IN = 1928;        // z rows (1 sca + 1927 emb)
constexpr int C1 = 964;

DEVFN float sigm(float x) { return 1.0f / (1.0f + __expf(-x)); }

DEVFN ushort f2b(float v) {       // fp32 -> bf16 (RNE)
    union { float f; unsigned u; } x; x.f = v;
    unsigned r = x.u + 0x7fffu + ((x.u >> 16) & 1u);
    return (ushort)(r >> 16);
}

// ---------------------------------------------------------------------------
// K1: conv_con (4x4 s2) + relu + maxpool 2x2 + fc_con  ->  sca[n][200]
__global__ void k_sca(const float* __restrict__ replay, const float* __restrict__ wc,
                      const float* __restrict__ bc, const float* __restrict__ fcw,
                      const float* __restrict__ fcb, float* __restrict__ sca) {
    const int n = blockIdx.x;                                 // 0..63
    const float* x = replay + (size_t)n * 8 * HW * HW;        // channel 0
    __shared__ __align__(16) float y[961];
    __shared__ float wcs[16];
    if (threadIdx.x < 16) wcs[threadIdx.x] = wc[threadIdx.x];
    const float bcv = bc[0];
    __syncthreads();
    for (int idx = threadIdx.x; idx < 961; idx += blockDim.x) {
        const int i = idx / 31, j = idx % 31;
        float m = 0.0f;
        #pragma unroll
        for (int di = 0; di < 2; ++di)
        #pragma unroll
        for (int dj = 0; dj < 2; ++dj) {
            const int ci = 2 * i + di, cj = 2 * j + dj;
            const int h0 = 2 * ci, w0 = 2 * cj;
            float acc = bcv;
            #pragma unroll
            for (int p = 0; p < 4; ++p)
            #pragma unroll
            for (int q = 0; q < 4; ++q)
                acc += x[(h0 + p) * HW + (w0 + q)] * wcs[p * 4 + q];
            m = fmaxf(m, fmaxf(acc, 0.0f));
        }
        y[idx] = m;
    }
    __syncthreads();
    for (int o = threadIdx.x; o < 200; o += blockDim.x) {
        float acc = fcb[o];
        const float* wr = fcw + (size_t)o * 961;
        for (int m = 0; m < 961; ++m) acc += y[m] * wr[m];
        sca[n * 200 + o] = acc;
    }
}

// ---------------------------------------------------------------------------
// K2a: Wsum[oc][kw] = sum_ic W1[oc][ic][kw]
__global__ void k_wsum(const float* __restrict__ w1, float* __restrict__ wsum) {
    const int oc = blockIdx.x;
    const float* wr = w1 + (size_t)oc * C1IN * 2;
    float s0 = 0.f, s1 = 0.f;
    for (int ic = threadIdx.x; ic < C1IN; ic += 64) {
        s0 += wr[ic * 2 + 0];
        s1 += wr[ic * 2 + 1];
    }
    #pragma unroll
    for (int off = 32; off > 0; off >>= 1) {
        s0 += __shfl_down(s0, off);
        s1 += __shfl_down(s1, off);
    }
    if (threadIdx.x == 0) { wsum[oc * 2] = s0; wsum[oc * 2 + 1] = s1; }
}

// K2b: SA[n][oc][kw] = sum over active emb rows of W1[oc][ic][kw]
__global__ void k_sa(const float* __restrict__ replay, const float* __restrict__ w1,
                     float* __restrict__ sa) {
    const int n = blockIdx.y;
    const int oc = blockIdx.x * blockDim.x + threadIdx.x;
    if (oc >= C1) return;
    const int chs[5]    = {1, 3, 5, 6, 7};
    const int scales[5] = {4, 2, 5, 2, 1914};
    const int offs[5]   = {0, 4, 6, 11, 13};
    float s0 = 0.f, s1 = 0.f;
    #pragma unroll
    for (int k = 0; k < 5; ++k) {
        int v = (int)replay[((size_t)n * 8 + chs[k]) * HW * HW];
        if (v > scales[k]) v = 0;
        if (v >= 1 && v <= scales[k] - 1) {
            const int ic = 1 + offs[k] + v;
            s0 += w1[((size_t)oc * C1IN + ic) * 2 + 0];
            s1 += w1[((size_t)oc * C1IN + ic) * 2 + 1];
        }
    }
    sa[(n * C1 + oc) * 2 + 0] = s0;
    sa[(n * C1 + oc) * 2 + 1] = s1;
}

// ---------------------------------------------------------------------------
// K3: cnn1 exact low-rank decomposition + relu + pool(1,2), writes im2col'd
// bf16 Xt2[nc=n*98+w][k=2*ic+kw] = p1val[n][ic][w+kw]; cols >= 1928 zeroed.
template <int OCT, int KP>
__global__ void k_cnn1(const float* __restrict__ sca, const float* __restrict__ emb,
                       const float* __restrict__ w1, const float* __restrict__ b1,
                       const float* __restrict__ wsum, const float* __restrict__ sa,
                       ushort* __restrict__ Xt2) {
    const int n = blockIdx.x;
    const int ocBase = blockIdx.y * OCT;       // grid.y = 62 -> cols up to 1984
    const int tx = threadIdx.x;
    __shared__ float ev[200], sv[200], dv[200];
    __shared__ float oscal[OCT][7];
    __shared__ float vals[OCT][100];
    for (int i = tx; i < 200; i += blockDim.x) {
        const float e0 = emb[i], e1 = emb[200 + i];
        ev[i] = e0;
        dv[i] = e1 - e0;
        sv[i] = sca[n * 200 + i] - e0;
    }
    for (int i = tx; i < OCT * 7; i += blockDim.x) {
        const int ocl = i / 7, f = i % 7;
        const int oc = ocBase + ocl;
        float v = 0.f;
        if (oc < C1) {
            switch (f) {
                case 0: v = wsum[oc * 2 + 0]; break;
                case 1: v = wsum[oc * 2 + 1]; break;
                case 2: v = b1[oc]; break;
                case 3: v = w1[(size_t)oc * C1IN * 2 + 0]; break;
                case 4: v = w1[(size_t)oc * C1IN * 2 + 1]; break;
                case 5: v = sa[(n * C1 + oc) * 2 + 0]; break;
                case 6: v = sa[(n * C1 + oc) * 2 + 1]; break;
            }
        }
        oscal[ocl][f] = v;
    }
    __syncthreads();
    for (int item = tx; item < OCT * 99; item += blockDim.x) {
        const int ocl = item / 99, u = item % 99;
        const int oc = ocBase + ocl;
        float res = 0.f;
        if (oc < C1) {
            const float ws0 = oscal[ocl][0], ws1 = oscal[ocl][1], bb = oscal[ocl][2];
            const float a0 = oscal[ocl][3], a1 = oscal[ocl][4];
            const float s0 = oscal[ocl][5], s1 = oscal[ocl][6];
            float r = -INFINITY;
            #pragma unroll
            for (int dw = 0; dw < 2; ++dw) {
                const int ww = 2 * u + dw;
                const float o = bb + ws0 * ev[ww] + ws1 * ev[ww + 1]
                                   + a0 * sv[ww] + a1 * sv[ww + 1]
                                   + s0 * dv[ww] + s1 * dv[ww + 1];
                r = fmaxf(r, o);
            }
            res = fmaxf(r, 0.0f);
        }
        vals[ocl][u] = res;
    }
    __syncthreads();
    // write tile: rows nc=n*98+w (w<98), cols 2*ocBase + c (c<2*OCT)
    for (int i = tx; i < 98 * (2 * OCT); i += blockDim.x) {
        const int w = i / (2 * OCT), c = i % (2 * OCT);
        const int ocl = c >> 1, kw = c & 1;
        Xt2[(size_t)(n * 98 + w) * KP + 2 * ocBase + c] = f2b(vals[ocl][w + kw]);
    }
}

// ---------------------------------------------------------------------------
// Weight -> padded bf16 [Mpad][KP]
__global__ void k_wbf(const float* __restrict__ w, ushort* __restrict__ A,
                      int OC, int K, int Mpad, int KP) {
    int idx = blockIdx.x * 256 + threadIdx.x;
    const int total = Mpad * KP;
    if (idx < total) {
        const int oc = idx / KP, k = idx - oc * KP;
        float v = (oc < OC && k < K) ? w[(size_t)oc * K + k] : 0.f;
        A[idx] = f2b(v);
    }
}

// im2col for layer3: Xt3[nc=n*48+w][k=2*ic+kw] = p2[n][ic][w+kw]; k>=964 -> 0
__global__ void k_im2col3(const float* __restrict__ p2, ushort* __restrict__ Xt3) {
    const int nc = blockIdx.x;                 // 3072
    const int n = nc / 48, w = nc % 48;
    for (int k = threadIdx.x; k < 1024; k += 256) {
        const int ic = k >> 1, kw = k & 1;
        float v = (ic < 482) ? p2[((size_t)n * 482 + ic) * 49 + w + kw] : 0.f;
        Xt3[(size_t)nc * 1024 + k] = f2b(v);
    }
}

// ---------------------------------------------------------------------------
// bf16 MFMA GEMM, C = A * Bt^T form: A[Mpad][KP], Bt[Npad][KP], fused
// bias+relu+pool(1,2) epilogue -> out[64][OCREAL][WOUT/2] fp32
template <int WOUT, int OCREAL, int KP>
__global__ __launch_bounds__(256) void k_gemm_conv(
    const ushort* __restrict__ A, const ushort* __restrict__ Bt,
    const float* __restrict__ bias, float* __restrict__ out) {
    constexpr int BK = 64;
    constexpr int LS = 72;                     // LDS row stride (shorts): 2-way max
    constexpr int UOUT = WOUT / 2;
    __shared__ ushort As[128 * LS];
    __shared__ ushort Bs[128 * LS];
    const int tx = threadIdx.x;
    const int nBase = blockIdx.x * 128;
    const int mBase = blockIdx.y * 128;
    const int wave = tx >> 6, lane = tx & 63;
    const int wm = wave >> 1, wn = wave & 1;
    const int lr = lane & 15;
    const int lk = lane >> 4;

    f32x4 acc[4][4] = {};
    uint4 ra[4], rb[4];
    const int NT = KP / BK;

    // prologue load (tile 0)
    #pragma unroll
    for (int p = 0; p < 4; ++p) {
        const int q = tx + p * 256;
        const int row = q >> 3, c = q & 7;
        ra[p] = *(const uint4*)&A[(size_t)(mBase + row) * KP + c * 8];
        rb[p] = *(const uint4*)&Bt[(size_t)(nBase + row) * KP + c * 8];
    }

    for (int kt = 0; kt < NT; ++kt) {
        __syncthreads();
        #pragma unroll
        for (int p = 0; p < 4; ++p) {
            const int q = tx + p * 256;
            const int row = q >> 3, c = q & 7;
            *(uint4*)&As[row * LS + c * 8] = ra[p];
            *(uint4*)&Bs[row * LS + c * 8] = rb[p];
        }
        __syncthreads();
        if (kt + 1 < NT) {
            const int k0 = (kt + 1) * BK;
            #pragma unroll
            for (int p = 0; p < 4; ++p) {
                const int q = tx + p * 256;
                const int row = q >> 3, c = q & 7;
                ra[p] = *(const uint4*)&A[(size_t)(mBase + row) * KP + k0 + c * 8];
                rb[p] = *(const uint4*)&Bt[(size_t)(nBase + row) * KP + k0 + c * 8];
            }
        }
        #pragma unroll
        for (int ks = 0; ks < 2; ++ks) {
            bf16x8 a[4], b[4];
            #pragma unroll
            for (int i = 0; i < 4; ++i) {
                a[i] = *(const bf16x8*)&As[(wm * 64 + i * 16 + lr) * LS + ks * 32 + lk * 8];
                b[i] = *(const bf16x8*)&Bs[(wn * 64 + i * 16 + lr) * LS + ks * 32 + lk * 8];
            }
            #pragma unroll
            for (int i = 0; i < 4; ++i)
                #pragma unroll
                for (int j = 0; j < 4; ++j)
                    acc[i][j] = __builtin_amdgcn_mfma_f32_16x16x32_bf16(a[i], b[j], acc[i][j], 0, 0, 0);
        }
    }

    // epilogue: pool adjacent cols (adjacent lanes), bias, relu, store
    #pragma unroll
    for (int i = 0; i < 4; ++i) {
        const int m0 = mBase + wm * 64 + i * 16 + lk * 4;
        #pragma unroll
        for (int j = 0; j < 4; ++j) {
            const int nc = nBase + wn * 64 + j * 16 + lr;
            #pragma unroll
            for (int r = 0; r < 4; ++r) {
                const float v = acc[i][j][r];
                const float vo = __shfl_xor(v, 1);
                const int m = m0 + r;
                if (((lane & 1) == 0) && (m < OCREAL)) {
                    const float pv = fmaxf(v, vo) + bias[m];
                    const int n = nc / WOUT, w = nc - n * WOUT;
                    out[((size_t)n * OCREAL + m) * UOUT + (w >> 1)] = fmaxf(pv, 0.0f);
                }
            }
        }
    }
}

// ---------------------------------------------------------------------------
// cnn4 (fp32, small): in [N][IC][WIN], w [OC][IC][2], out [N][OC][WIN-1]
template <int IC, int OC, int WIN, bool POOL>
__global__ __launch_bounds__(256) void k_conv(const float* __restrict__ in,
                                              const float* __restrict__ w,
                                              const float* __restrict__ bias,
                                              float* __restrict__ out) {
    constexpr int WOUT = WIN - 1;
    constexpr int NOUT = POOL ? (WOUT / 2) : WOUT;
    constexpr int OCT = 32;
    constexpr int KT = 32;
    constexpr int MAXU = (NOUT + 15) / 16;
    constexpr int PSTRIDE = (WIN % 2) ? (WIN + 1) : WIN;
    constexpr int WSTRIDE = 2 * KT + 2;

    __shared__ __align__(16) float pt[KT * PSTRIDE];
    __shared__ __align__(16) float wt[OCT * WSTRIDE];

    const int n = blockIdx.x;
    const int ocBase = blockIdx.y * OCT;
    const int tx = threadIdx.x;
    const int ocg = tx >> 4;
    const int ol = tx & 15;
    const int oc0 = ocBase + 2 * ocg;
    const int oc1 = oc0 + 1;

    float acc[2][2][MAXU];
    #pragma unroll
    for (int a = 0; a < 2; ++a)
        #pragma unroll
        for (int q = 0; q < 2; ++q)
            #pragma unroll
            for (int r = 0; r < MAXU; ++r) acc[a][q][r] = 0.f;

    const float* inn = in + (size_t)n * IC * WIN;

    for (int icb = 0; icb < IC; icb += KT) {
        const int kt = min(KT, IC - icb);
        __syncthreads();
        for (int i = tx; i < KT * WIN; i += 256) {
            const int r = i / WIN, c = i - r * WIN;
            pt[r * PSTRIDE + c] = (r < kt) ? inn[icb * WIN + i] : 0.0f;
        }
        for (int i = tx; i < OCT * 2 * KT; i += 256) {
            const int r = i / (2 * KT), c = i - r * (2 * KT);
            const int oc = ocBase + r;
            const int ic = icb + (c >> 1);
            float v = 0.f;
            if (oc < OC && ic < IC) v = w[((size_t)oc * IC + ic) * 2 + (c & 1)];
            wt[r * WSTRIDE + c] = v;
        }
        __syncthreads();
        #pragma unroll 4
        for (int ic = 0; ic < KT; ++ic) {
            const float2 w0 = *(const float2*)&wt[(2 * ocg) * WSTRIDE + 2 * ic];
            const float2 w1v = *(const float2*)&wt[(2 * ocg + 1) * WSTRIDE + 2 * ic];
            #pragma unroll
            for (int r = 0; r < MAXU; ++r) {
                const int u = ol + 16 * r;
                if (u < NOUT) {
                    const float p0 = pt[ic * PSTRIDE + u];
                    const float p1v = pt[ic * PSTRIDE + u + 1];
                    acc[0][0][r] += w0.x * p0 + w0.y * p1v;
                    acc[1][0][r] += w1v.x * p0 + w1v.y * p1v;
                }
            }
        }
    }

    const float b0 = (oc0 < OC) ? bias[oc0] : 0.f;
    const float b1v = (oc1 < OC) ? bias[oc1] : 0.f;
    float* outn = out + (size_t)n * OC * NOUT;
    #pragma unroll
    for (int r = 0; r < MAXU; ++r) {
        const int u = ol + 16 * r;
        if (u < NOUT) {
            if (oc0 < OC) outn[oc0 * NOUT + u] = fmaxf(acc[0][0][r] + b0, 0.f);
            if (oc1 < OC) outn[oc1 * NOUT + u] = fmaxf(acc[1][0][r] + b1v, 0.f);
        }
    }
}

// ---------------------------------------------------------------------------
// fc_cnn: seq[n][100] = z4[n][2300] @ W.T + b
__global__ void k_fc_cnn(const float* __restrict__ z4, const float* __restrict__ w,
                         const float* __restrict__ b, float* __restrict__ seq) {
    const int n = blockIdx.x;
    __shared__ __align__(16) float zb[2300];
    for (int i = threadIdx.x; i < 2300; i += blockDim.x) zb[i] = z4[(size_t)n * 2300 + i];
    __syncthreads();
    if (threadIdx.x < 100) {
        const int o = threadIdx.x;
        const float4* wr = (const float4*)(w + (size_t)o * 2300);
        const float4* zb4 = (const float4*)zb;
        float4 a = {0.f, 0.f, 0.f, 0.f};
        for (int m = 0; m < 575; ++m) {
            const float4 wv = wr[m];
            const float4 zv = zb4[m];
            a.x += wv.x * zv.x; a.y += wv.y * zv.y;
            a.z += wv.z * zv.z; a.w += wv.w * zv.w;
        }
        seq[n * 100 + o] = b[o] + a.x + a.y + a.z + a.w;
    }
}

// xg[n][400] = seq[n] @ W_ih.T + b_ih + b_hh
__global__ void k_xg(const float* __restrict__ seq, const float* __restrict__ wih,
                     const float* __restrict__ bih, const float* __restrict__ bhh,
                     float* __restrict__ xg) {
    const int n = blockIdx.x;
    __shared__ __align__(16) float s[100];
    if (threadIdx.x < 100) s[threadIdx.x] = seq[n * 100 + threadIdx.x];
    __syncthreads();
    const int g = threadIdx.x;
    if (g < 400) {
        const float4* wr = (const float4*)(wih + (size_t)g * 100);
        const float4* s4 = (const float4*)s;
        float4 a = {0.f, 0.f, 0.f, 0.f};
        #pragma unroll
        for (int m = 0; m < 25; ++m) {
            const float4 wv = wr[m];
            const float4 sv = s4[m];
            a.x += wv.x * sv.x; a.y += wv.y * sv.y;
            a.z += wv.z * sv.z; a.w += wv.w * sv.w;
        }
        xg[n * 400 + g] = bih[g] + bhh[g] + a.x + a.y + a.z + a.w;
    }
}

__global__ void k_whhT(const float* __restrict__ whh, float* __restrict__ whhT) {
    const int i = blockIdx.x * blockDim.x + threadIdx.x;
    if (i < 40000) {
        const int g = i / 100, m = i - g * 100;
        whhT[m * 400 + g] = whh[i];
    }
}

// LSTM recurrence: one block per batch; weight column held in registers.
__global__ __launch_bounds__(512) void k_lstm(const float* __restrict__ xg,
                                              const float* __restrict__ whhT,
                                              const float* __restrict__ fw,
                                              const float* __restrict__ fb,
                                              float* __restrict__ outp) {
    const int b = blockIdx.x;
    const int tx = threadIdx.x;
    __shared__ float h[100], g[400];
    float wreg[100];
    if (tx < 400) {
        #pragma unroll
        for (int m = 0; m < 100; ++m) wreg[m] = whhT[m * 400 + tx];
    }
    float cc = 0.f;
    if (tx < 100) h[tx] = 0.f;
    __syncthreads();
    for (int t = 0; t < T_; ++t) {
        if (tx < 400) {
            float acc = xg[(size_t)(b * T_ + t) * 400 + tx];
            #pragma unroll
            for (int m = 0; m < 100; ++m) acc += h[m] * wreg[m];
            g[tx] = acc;
        }
        __syncthreads();
        if (tx < 100) {
            const float iv = g[tx], fv = g[100 + tx];
            const float gv = g[200 + tx], ov = g[300 + tx];
            cc = sigm(fv) * cc + sigm(iv) * tanhf(gv);
            h[tx] = sigm(ov) * tanhf(cc);
        }
        __syncthreads();
    }
    if (tx < 2) {
        float acc = fb[tx];
        for (int j = 0; j < 100; ++j) acc += h[j] * fw[tx * 100 + j];
        outp[b * 2 + tx] = acc;
    }
}

// ---------------------------------------------------------------------------
extern "C" void kernel_launch(void* const* d_in, const int* in_sizes, int n_in,
                              void* d_out, int out_size, void* d_ws, size_t ws_size,
                              hipStream_t stream) {
    (void)in_sizes; (void)n_in; (void)out_size; (void)ws_size;
    const float* replay = (const float*)d_in[0];
    const float* emb    = (const float*)d_in[1];
    const float* ccw    = (const float*)d_in[2];
    const float* ccb    = (const float*)d_in[3];
    const float* fcw    = (const float*)d_in[4];
    const float* fcb    = (const float*)d_in[5];
    const float* w1     = (const float*)d_in[6];
    const float* b1     = (const float*)d_in[7];
    const float* w2     = (const float*)d_in[8];
    const float* b2     = (const float*)d_in[9];
    const float* w3     = (const float*)d_in[10];
    const float* b3     = (const float*)d_in[11];
    const float* w4     = (const float*)d_in[12];
    const float* b4     = (const float*)d_in[13];
    const float* fcnw   = (const float*)d_in[14];
    const float* fcnb   = (const float*)d_in[15];
    const float* wih    = (const float*)d_in[16];
    const float* whh    = (const float*)d_in[17];
    const float* bih    = (const float*)d_in[18];
    const float* bhh    = (const float*)d_in[19];
    const float* fow    = (const float*)d_in[20];
    const float* fob    = (const float*)d_in[21];

    float* ws = (float*)d_ws;
    float*  sca  = ws + 0;                         // 12800
    float*  wsum = ws + 12800;                     // 1928
    float*  sa   = ws + 14784;                     // 123392
    float*  seq  = ws + 138176;                    // 6400
    float*  xg   = ws + 144576;                    // 25600
    float*  whhT = ws + 170176;                    // 40000
    float*  p2   = ws + 210176;                    // 64*482*49 = 1511552
    ushort* A2   = (ushort*)(ws + 1721728);        // 512*1984 shorts
    ushort* A3   = (ushort*)(ws + 2229632);        // 256*1024 shorts
    ushort* Xt2  = (ushort*)(ws + 2360704);        // 6272*1984 shorts (24.9 MB)
    // aliases inside the (dead-after-gemm1) Xt2 region:
    ushort* Xt3  = (ushort*)(ws + 2360704);        // 3072*1024 shorts (first 1.57M fl)
    float*  p3   = ws + 3960704;                   // 64*241*24 = 370176
    float*  z4   = ws + 4330880;                   // 64*100*23 = 147200
    float*  outp = (float*)d_out;

    k_sca<<<64, 256, 0, stream>>>(replay, ccw, ccb, fcw, fcb, sca);
    k_wsum<<<964, 64, 0, stream>>>(w1, wsum);
    k_sa<<<dim3(4, 64), 256, 0, stream>>>(replay, w1, sa);
    k_whhT<<<157, 256, 0, stream>>>(whh, whhT);
    k_wbf<<<3968, 256, 0, stream>>>(w2, A2, 482, 1928, 512, 1984);
    k_wbf<<<1024, 256, 0, stream>>>(w3, A3, 241, 964, 256, 1024);
    k_cnn1<16, 1984><<<dim3(64, 62), 256, 0, stream>>>(sca, emb, w1, b1, wsum, sa, Xt2);
    k_gemm_conv<98, 482, 1984><<<dim3(49, 4), 256, 0, stream>>>(A2, Xt2, b2, p2);
    k_im2col3<<<3072, 256, 0, stream>>>(p2, Xt3);
    k_gemm_conv<48, 241, 1024><<<dim3(24, 2), 256, 0, stream>>>(A3, Xt3, b3, p3);
    k_conv<241, 100, 24, false><<<dim3(64, 4), 256, 0, stream>>>(p3, w4, b4, z4);
    k_fc_cnn<<<64, 128, 0, stream>>>(z4, fcnw, fcnb, seq);
    k_xg<<<64, 512, 0, stream>>>(seq, wih, bih, bhh, xg);
    k_lstm<<<2, 512, 0, stream>>>(xg, whhT, fow, fob, outp);
}

// Round 3
// 261.492 us; speedup vs baseline: 3.4848x; 1.6072x over previous
//
#include <hip/hip_runtime.h>
#include <math.h>

#define DEVFN __device__ __forceinline__

typedef __bf16 bf16x8 __attribute__((ext_vector_type(8)));
typedef float f32x4 __attribute__((ext_vector_type(4)));

constexpr int T_ = 32;
constexpr int HW = 128;
constexpr int C1IN = 1928;        // cnn1 input channels
constexpr int C1 = 964;

DEVFN float sigm(float x) { return 1.0f / (1.0f + __expf(-x)); }

DEVFN ushort f2b(float v) {       // fp32 -> bf16 (RNE)
    union { float f; unsigned u; } x; x.f = v;
    unsigned r = x.u + 0x7fffu + ((x.u >> 16) & 1u);
    return (ushort)(r >> 16);
}

// ---------------------------------------------------------------------------
// conv_con (4x4 s2) + relu + maxpool 2x2 -> y[n][961]
__global__ void k_sca_conv(const float* __restrict__ replay, const float* __restrict__ wc,
                           const float* __restrict__ bc, float* __restrict__ y) {
    const int n = blockIdx.x;
    const int idx = blockIdx.y * 256 + threadIdx.x;
    if (idx >= 961) return;
    const float* x = replay + (size_t)n * 8 * HW * HW;     // channel 0
    float wr_[16];
    #pragma unroll
    for (int t = 0; t < 16; ++t) wr_[t] = wc[t];
    const float bcv = bc[0];
    const int i = idx / 31, j = idx % 31;
    float m = 0.0f;
    #pragma unroll
    for (int di = 0; di < 2; ++di)
    #pragma unroll
    for (int dj = 0; dj < 2; ++dj) {
        const int h0 = 2 * (2 * i + di), w0 = 2 * (2 * j + dj);
        float acc = bcv;
        #pragma unroll
        for (int p = 0; p < 4; ++p)
        #pragma unroll
        for (int q = 0; q < 4; ++q)
            acc += x[(h0 + p) * HW + (w0 + q)] * wr_[p * 4 + q];
        m = fmaxf(m, fmaxf(acc, 0.0f));
    }
    y[n * 961 + idx] = m;
}

// fc_con: sca[n][o] = y[n] . fcw[o] + fcb[o]   (one wave per output)
__global__ void k_sca_fc(const float* __restrict__ y, const float* __restrict__ fcw,
                         const float* __restrict__ fcb, float* __restrict__ sca) {
    const int n = blockIdx.x;
    const int wid = threadIdx.x >> 6, lane = threadIdx.x & 63;
    const int o = blockIdx.y * 4 + wid;                    // < 200
    float acc = 0.f;
    for (int m = lane; m < 961; m += 64)
        acc += y[n * 961 + m] * fcw[(size_t)o * 961 + m];
    #pragma unroll
    for (int off = 32; off > 0; off >>= 1) acc += __shfl_down(acc, off);
    if (lane == 0) sca[n * 200 + o] = acc + fcb[o];
}

// ---------------------------------------------------------------------------
__global__ void k_wsum(const float* __restrict__ w1, float* __restrict__ wsum) {
    const int oc = blockIdx.x;
    const float* wr = w1 + (size_t)oc * C1IN * 2;
    float s0 = 0.f, s1 = 0.f;
    for (int ic = threadIdx.x; ic < C1IN; ic += 64) {
        s0 += wr[ic * 2 + 0];
        s1 += wr[ic * 2 + 1];
    }
    #pragma unroll
    for (int off = 32; off > 0; off >>= 1) {
        s0 += __shfl_down(s0, off);
        s1 += __shfl_down(s1, off);
    }
    if (threadIdx.x == 0) { wsum[oc * 2] = s0; wsum[oc * 2 + 1] = s1; }
}

__global__ void k_sa(const float* __restrict__ replay, const float* __restrict__ w1,
                     float* __restrict__ sa) {
    const int n = blockIdx.y;
    const int oc = blockIdx.x * blockDim.x + threadIdx.x;
    if (oc >= C1) return;
    const int chs[5]    = {1, 3, 5, 6, 7};
    const int scales[5] = {4, 2, 5, 2, 1914};
    const int offs[5]   = {0, 4, 6, 11, 13};
    float s0 = 0.f, s1 = 0.f;
    #pragma unroll
    for (int k = 0; k < 5; ++k) {
        int v = (int)replay[((size_t)n * 8 + chs[k]) * HW * HW];
        if (v > scales[k]) v = 0;
        if (v >= 1 && v <= scales[k] - 1) {
            const int ic = 1 + offs[k] + v;
            s0 += w1[((size_t)oc * C1IN + ic) * 2 + 0];
            s1 += w1[((size_t)oc * C1IN + ic) * 2 + 1];
        }
    }
    sa[(n * C1 + oc) * 2 + 0] = s0;
    sa[(n * C1 + oc) * 2 + 1] = s1;
}

// ---------------------------------------------------------------------------
// cnn1 low-rank decomposition + relu + pool(1,2), writes im2col'd bf16
// Xt2[nc=n*98+w][k=2*ic+kw]; cols >= 1928 zeroed.
template <int OCT, int KP>
__global__ void k_cnn1(const float* __restrict__ sca, const float* __restrict__ emb,
                       const float* __restrict__ w1, const float* __restrict__ b1,
                       const float* __restrict__ wsum, const float* __restrict__ sa,
                       ushort* __restrict__ Xt2) {
    const int n = blockIdx.x;
    const int ocBase = blockIdx.y * OCT;
    const int tx = threadIdx.x;
    __shared__ float ev[200], sv[200], dv[200];
    __shared__ float oscal[OCT][7];
    __shared__ float vals[OCT][100];
    for (int i = tx; i < 200; i += blockDim.x) {
        const float e0 = emb[i], e1 = emb[200 + i];
        ev[i] = e0;
        dv[i] = e1 - e0;
        sv[i] = sca[n * 200 + i] - e0;
    }
    for (int i = tx; i < OCT * 7; i += blockDim.x) {
        const int ocl = i / 7, f = i % 7;
        const int oc = ocBase + ocl;
        float v = 0.f;
        if (oc < C1) {
            switch (f) {
                case 0: v = wsum[oc * 2 + 0]; break;
                case 1: v = wsum[oc * 2 + 1]; break;
                case 2: v = b1[oc]; break;
                case 3: v = w1[(size_t)oc * C1IN * 2 + 0]; break;
                case 4: v = w1[(size_t)oc * C1IN * 2 + 1]; break;
                case 5: v = sa[(n * C1 + oc) * 2 + 0]; break;
                case 6: v = sa[(n * C1 + oc) * 2 + 1]; break;
            }
        }
        oscal[ocl][f] = v;
    }
    __syncthreads();
    for (int item = tx; item < OCT * 99; item += blockDim.x) {
        const int ocl = item / 99, u = item % 99;
        const int oc = ocBase + ocl;
        float res = 0.f;
        if (oc < C1) {
            const float ws0 = oscal[ocl][0], ws1 = oscal[ocl][1], bb = oscal[ocl][2];
            const float a0 = oscal[ocl][3], a1 = oscal[ocl][4];
            const float s0 = oscal[ocl][5], s1 = oscal[ocl][6];
            float r = -INFINITY;
            #pragma unroll
            for (int dw = 0; dw < 2; ++dw) {
                const int ww = 2 * u + dw;
                const float o = bb + ws0 * ev[ww] + ws1 * ev[ww + 1]
                                   + a0 * sv[ww] + a1 * sv[ww + 1]
                                   + s0 * dv[ww] + s1 * dv[ww + 1];
                r = fmaxf(r, o);
            }
            res = fmaxf(r, 0.0f);
        }
        vals[ocl][u] = res;
    }
    __syncthreads();
    for (int i = tx; i < 98 * (2 * OCT); i += blockDim.x) {
        const int w = i / (2 * OCT), c = i % (2 * OCT);
        const int ocl = c >> 1, kw = c & 1;
        Xt2[(size_t)(n * 98 + w) * KP + 2 * ocBase + c] = f2b(vals[ocl][w + kw]);
    }
}

// ---------------------------------------------------------------------------
__global__ void k_wbf(const float* __restrict__ w, ushort* __restrict__ A,
                      int OC, int K, int Mpad, int KP) {
    int idx = blockIdx.x * 256 + threadIdx.x;
    const int total = Mpad * KP;
    if (idx < total) {
        const int oc = idx / KP, k = idx - oc * KP;
        float v = (oc < OC && k < K) ? w[(size_t)oc * K + k] : 0.f;
        A[idx] = f2b(v);
    }
}

// im2col for layer3 (bf16 in/out): Xt3[nc=n*48+w][2ic+kw] = p2b[n][ic][w+kw]
__global__ void k_im2col3(const ushort* __restrict__ p2b, ushort* __restrict__ Xt3) {
    const int nc = blockIdx.x;                 // 3072
    const int n = nc / 48, w = nc % 48;
    for (int k = threadIdx.x; k < 1024; k += 256) {
        const int ic = k >> 1, kw = k & 1;
        ushort v = (ic < 482) ? p2b[((size_t)n * 482 + ic) * 49 + w + kw] : (ushort)0;
        Xt3[(size_t)nc * 1024 + k] = v;
    }
}

// ---------------------------------------------------------------------------
// bf16 MFMA GEMM, C = A * Bt^T: A[Mpad][KP], Bt[N][KP]. 4 waves (2x2), each
// computes (BM/2)x(BN/2). Double-buffered LDS, one barrier per K-step,
// XCD-grouped block swizzle. Fused bias+relu+pool(1,2) epilogue.
template <int BM, int BN, int OCREAL, int WOUT, int KP, bool OUTBF, int NX, int NY>
__global__ __launch_bounds__(256) void k_gemm_conv(
    const ushort* __restrict__ A, const ushort* __restrict__ Bt,
    const float* __restrict__ bias, void* __restrict__ outv) {
    constexpr int BK = 64;
    constexpr int LS = 72;
    constexpr int RA = BM / 32, RB = BN / 32;
    constexpr int HM = BM / 2, HN = BN / 2;
    constexpr int FM = HM / 16, FN = HN / 16;
    constexpr int UOUT = WOUT / 2;
    constexpr int NT = KP / BK;
    constexpr int GRP = 8 * NY;

    __shared__ __align__(16) ushort As[2 * BM * LS];
    __shared__ __align__(16) ushort Bs[2 * BN * LS];

    const int f = blockIdx.x;
    const int x = (f / GRP) * 8 + (f & 7);
    const int yb = (f % GRP) >> 3;
    if (x >= NX) return;
    const int nBase = x * BN;
    const int mBase = yb * BM;

    const int tx = threadIdx.x;
    const int wave = tx >> 6, lane = tx & 63;
    const int wm = wave >> 1, wn = wave & 1;
    const int lr = lane & 15, lk = lane >> 4;

    f32x4 acc[FM][FN] = {};
    uint4 ra[RA], rb[RB];

    auto LOAD = [&](int kt) {
        const int k0 = kt * BK;
        #pragma unroll
        for (int p = 0; p < RA; ++p) {
            const int q = tx + p * 256, row = q >> 3, c = q & 7;
            ra[p] = *(const uint4*)&A[(size_t)(mBase + row) * KP + k0 + c * 8];
        }
        #pragma unroll
        for (int p = 0; p < RB; ++p) {
            const int q = tx + p * 256, row = q >> 3, c = q & 7;
            rb[p] = *(const uint4*)&Bt[(size_t)(nBase + row) * KP + k0 + c * 8];
        }
    };
    auto STORE = [&](int buf) {
        #pragma unroll
        for (int p = 0; p < RA; ++p) {
            const int q = tx + p * 256, row = q >> 3, c = q & 7;
            *(uint4*)&As[buf * BM * LS + row * LS + c * 8] = ra[p];
        }
        #pragma unroll
        for (int p = 0; p < RB; ++p) {
            const int q = tx + p * 256, row = q >> 3, c = q & 7;
            *(uint4*)&Bs[buf * BN * LS + row * LS + c * 8] = rb[p];
        }
    };

    LOAD(0);
    STORE(0);
    if (NT > 1) LOAD(1);
    __syncthreads();

    for (int kt = 0; kt < NT; ++kt) {
        const int cur = kt & 1;
        #pragma unroll
        for (int ks = 0; ks < 2; ++ks) {
            bf16x8 a[FM], b[FN];
            #pragma unroll
            for (int i = 0; i < FM; ++i)
                a[i] = *(const bf16x8*)&As[cur * BM * LS + (wm * HM + i * 16 + lr) * LS + ks * 32 + lk * 8];
            #pragma unroll
            for (int j = 0; j < FN; ++j)
                b[j] = *(const bf16x8*)&Bs[cur * BN * LS + (wn * HN + j * 16 + lr) * LS + ks * 32 + lk * 8];
            #pragma unroll
            for (int i = 0; i < FM; ++i)
                #pragma unroll
                for (int j = 0; j < FN; ++j)
                    acc[i][j] = __builtin_amdgcn_mfma_f32_16x16x32_bf16(a[i], b[j], acc[i][j], 0, 0, 0);
        }
        if (kt + 1 < NT) {
            STORE(cur ^ 1);
            if (kt + 2 < NT) LOAD(kt + 2);
        }
        __syncthreads();
    }

    ushort* outb = (ushort*)outv;
    float*  outf = (float*)outv;
    #pragma unroll
    for (int i = 0; i < FM; ++i) {
        const int m0 = mBase + wm * HM + i * 16 + lk * 4;
        #pragma unroll
        for (int j = 0; j < FN; ++j) {
            const int nc = nBase + wn * HN + j * 16 + lr;
            #pragma unroll
            for (int r = 0; r < 4; ++r) {
                const float v = acc[i][j][r];
                const float vo = __shfl_xor(v, 1);
                const int m = m0 + r;
                if (((lane & 1) == 0) && (m < OCREAL)) {
                    const float pv = fmaxf(v, vo) + bias[m];
                    const float val = fmaxf(pv, 0.0f);
                    const int n = nc / WOUT, w = nc - n * WOUT;
                    const size_t oi = ((size_t)n * OCREAL + m) * UOUT + (w >> 1);
                    if (OUTBF) outb[oi] = f2b(val);
                    else       outf[oi] = val;
                }
            }
        }
    }
}

// ---------------------------------------------------------------------------
// cnn4 (fp32, small): in [N][IC][WIN], w [OC][IC][2], out [N][OC][WIN-1]
template <int IC, int OC, int WIN>
__global__ __launch_bounds__(256) void k_conv(const float* __restrict__ in,
                                              const float* __restrict__ w,
                                              const float* __restrict__ bias,
                                              float* __restrict__ out) {
    constexpr int NOUT = WIN - 1;
    constexpr int OCT = 32;
    constexpr int KT = 32;
    constexpr int MAXU = (NOUT + 15) / 16;
    constexpr int PSTRIDE = (WIN % 2) ? (WIN + 1) : WIN;
    constexpr int WSTRIDE = 2 * KT + 2;

    __shared__ __align__(16) float pt[KT * PSTRIDE];
    __shared__ __align__(16) float wt[OCT * WSTRIDE];

    const int n = blockIdx.x;
    const int ocBase = blockIdx.y * OCT;
    const int tx = threadIdx.x;
    const int ocg = tx >> 4;
    const int ol = tx & 15;
    const int oc0 = ocBase + 2 * ocg;
    const int oc1 = oc0 + 1;

    float acc[2][MAXU];
    #pragma unroll
    for (int a = 0; a < 2; ++a)
        #pragma unroll
        for (int r = 0; r < MAXU; ++r) acc[a][r] = 0.f;

    const float* inn = in + (size_t)n * IC * WIN;

    for (int icb = 0; icb < IC; icb += KT) {
        const int kt = min(KT, IC - icb);
        __syncthreads();
        for (int i = tx; i < KT * WIN; i += 256) {
            const int r = i / WIN, c = i - r * WIN;
            pt[r * PSTRIDE + c] = (r < kt) ? inn[icb * WIN + i] : 0.0f;
        }
        for (int i = tx; i < OCT * 2 * KT; i += 256) {
            const int r = i / (2 * KT), c = i - r * (2 * KT);
            const int oc = ocBase + r;
            const int ic = icb + (c >> 1);
            float v = 0.f;
            if (oc < OC && ic < IC) v = w[((size_t)oc * IC + ic) * 2 + (c & 1)];
            wt[r * WSTRIDE + c] = v;
        }
        __syncthreads();
        #pragma unroll 4
        for (int ic = 0; ic < KT; ++ic) {
            const float2 w0 = *(const float2*)&wt[(2 * ocg) * WSTRIDE + 2 * ic];
            const float2 w1v = *(const float2*)&wt[(2 * ocg + 1) * WSTRIDE + 2 * ic];
            #pragma unroll
            for (int r = 0; r < MAXU; ++r) {
                const int u = ol + 16 * r;
                if (u < NOUT) {
                    const float p0 = pt[ic * PSTRIDE + u];
                    const float p1v = pt[ic * PSTRIDE + u + 1];
                    acc[0][r] += w0.x * p0 + w0.y * p1v;
                    acc[1][r] += w1v.x * p0 + w1v.y * p1v;
                }
            }
        }
    }

    const float b0 = (oc0 < OC) ? bias[oc0] : 0.f;
    const float b1v = (oc1 < OC) ? bias[oc1] : 0.f;
    float* outn = out + (size_t)n * OC * NOUT;
    #pragma unroll
    for (int r = 0; r < MAXU; ++r) {
        const int u = ol + 16 * r;
        if (u < NOUT) {
            if (oc0 < OC) outn[oc0 * NOUT + u] = fmaxf(acc[0][r] + b0, 0.f);
            if (oc1 < OC) outn[oc1 * NOUT + u] = fmaxf(acc[1][r] + b1v, 0.f);
        }
    }
}

// ---------------------------------------------------------------------------
// fc_cnn: seq[n][o] = z4[n][2300] . W[o] + b[o]   (one wave per output)
__global__ void k_fc_cnn(const float* __restrict__ z4, const float* __restrict__ w,
                         const float* __restrict__ b, float* __restrict__ seq) {
    const int n = blockIdx.x;
    const int wid = threadIdx.x >> 6, lane = threadIdx.x & 63;
    const int o = blockIdx.y * 4 + wid;                    // < 100
    const float4* zr = (const float4*)(z4 + (size_t)n * 2300);
    const float4* wr = (const float4*)(w + (size_t)o * 2300);
    float acc = 0.f;
    for (int m = lane; m < 575; m += 64) {
        const float4 wv = wr[m];
        const float4 zv = zr[m];
        acc += wv.x * zv.x + wv.y * zv.y + wv.z * zv.z + wv.w * zv.w;
    }
    #pragma unroll
    for (int off = 32; off > 0; off >>= 1) acc += __shfl_down(acc, off);
    if (lane == 0) seq[n * 100 + o] = acc + b[o];
}

// xg (PERMUTED gate layout p: gate=(p%4), unit=p/4) = seq @ W_ih.T + b_ih + b_hh
__global__ void k_xg(const float* __restrict__ seq, const float* __restrict__ wih,
                     const float* __restrict__ bih, const float* __restrict__ bhh,
                     float* __restrict__ xg) {
    const int n = blockIdx.x;
    __shared__ __align__(16) float s[100];
    if (threadIdx.x < 100) s[threadIdx.x] = seq[n * 100 + threadIdx.x];
    __syncthreads();
    const int p = threadIdx.x;
    if (p < 400) {
        const int go = (p & 3) * 100 + (p >> 2);
        const float4* wr = (const float4*)(wih + (size_t)go * 100);
        const float4* s4 = (const float4*)s;
        float4 a = {0.f, 0.f, 0.f, 0.f};
        #pragma unroll
        for (int m = 0; m < 25; ++m) {
            const float4 wv = wr[m];
            const float4 sv = s4[m];
            a.x += wv.x * sv.x; a.y += wv.y * sv.y;
            a.z += wv.z * sv.z; a.w += wv.w * sv.w;
        }
        xg[n * 400 + p] = bih[go] + bhh[go] + a.x + a.y + a.z + a.w;
    }
}

// whhT[m][p] = whh[go(p)][m] with permuted p
__global__ void k_whhT(const float* __restrict__ whh, float* __restrict__ whhT) {
    const int i = blockIdx.x * blockDim.x + threadIdx.x;
    if (i < 40000) {
        const int m = i / 400, p = i - m * 400;
        const int go = (p & 3) * 100 + (p >> 2);
        whhT[m * 400 + p] = whh[go * 100 + m];
    }
}

// LSTM: one block per batch; gate quadruple within a lane-quad -> 1 barrier/step
__global__ __launch_bounds__(512) void k_lstm(const float* __restrict__ xg,
                                              const float* __restrict__ whhT,
                                              const float* __restrict__ fw,
                                              const float* __restrict__ fb,
                                              float* __restrict__ outp) {
    const int bb = blockIdx.x;
    const int tx = threadIdx.x;
    __shared__ __align__(16) float hb[2][104];
    float wreg[100];
    if (tx < 400) {
        #pragma unroll
        for (int m = 0; m < 100; ++m) wreg[m] = whhT[m * 400 + tx];
    }
    float creg = 0.f;
    if (tx < 104) { hb[0][tx] = 0.f; hb[1][tx] = 0.f; }
    float xnext = (tx < 400) ? xg[(size_t)(bb * T_) * 400 + tx] : 0.f;
    __syncthreads();
    const int lane = tx & 63, base = lane & ~3;
    for (int t = 0; t < T_; ++t) {
        float acc = 0.f;
        if (tx < 400) {
            acc = xnext;
            if (t + 1 < T_) xnext = xg[(size_t)(bb * T_ + t + 1) * 400 + tx];
            const float4* h4 = (const float4*)&hb[t & 1][0];
            #pragma unroll
            for (int m4 = 0; m4 < 25; ++m4) {
                const float4 hv = h4[m4];
                acc += hv.x * wreg[4 * m4 + 0] + hv.y * wreg[4 * m4 + 1]
                     + hv.z * wreg[4 * m4 + 2] + hv.w * wreg[4 * m4 + 3];
            }
        }
        const float gI = __shfl(acc, base + 0);
        const float gF = __shfl(acc, base + 1);
        const float gG = __shfl(acc, base + 2);
        const float gO = __shfl(acc, base + 3);
        if (tx < 400) {
            const float cn = sigm(gF) * creg + sigm(gI) * tanhf(gG);
            creg = cn;
            if ((tx & 3) == 0) hb[(t + 1) & 1][tx >> 2] = sigm(gO) * tanhf(cn);
        }
        __syncthreads();
    }
    if (tx < 2) {
        float acc = fb[tx];
        for (int j = 0; j < 100; ++j) acc += hb[0][j] * fw[tx * 100 + j];
        outp[bb * 2 + tx] = acc;
    }
}

// ---------------------------------------------------------------------------
extern "C" void kernel_launch(void* const* d_in, const int* in_sizes, int n_in,
                              void* d_out, int out_size, void* d_ws, size_t ws_size,
                              hipStream_t stream) {
    (void)in_sizes; (void)n_in; (void)out_size; (void)ws_size;
    const float* replay = (const float*)d_in[0];
    const float* emb    = (const float*)d_in[1];
    const float* ccw    = (const float*)d_in[2];
    const float* ccb    = (const float*)d_in[3];
    const float* fcw    = (const float*)d_in[4];
    const float* fcb    = (const float*)d_in[5];
    const float* w1     = (const float*)d_in[6];
    const float* b1     = (const float*)d_in[7];
    const float* w2     = (const float*)d_in[8];
    const float* b2     = (const float*)d_in[9];
    const float* w3     = (const float*)d_in[10];
    const float* b3     = (const float*)d_in[11];
    const float* w4     = (const float*)d_in[12];
    const float* b4     = (const float*)d_in[13];
    const float* fcnw   = (const float*)d_in[14];
    const float* fcnb   = (const float*)d_in[15];
    const float* wih    = (const float*)d_in[16];
    const float* whh    = (const float*)d_in[17];
    const float* bih    = (const float*)d_in[18];
    const float* bhh    = (const float*)d_in[19];
    const float* fow    = (const float*)d_in[20];
    const float* fob    = (const float*)d_in[21];

    float* ws = (float*)d_ws;
    float*  sca  = ws + 0;                      // 12800
    float*  wsum = ws + 12800;                  // 1928 (pad 2048)
    float*  sa   = ws + 14848;                  // 123392
    float*  seq  = ws + 138240;                 // 6400
    float*  xg   = ws + 144640;                 // 25600
    float*  whhT = ws + 170240;                 // 40000
    ushort* p2b  = (ushort*)(ws + 210240);      // 64*482*49 sh = 755776 fl
    ushort* A2   = (ushort*)(ws + 966016);      // 512*1984 sh = 507904 fl
    ushort* A3   = (ushort*)(ws + 1473920);     // 256*1024 sh = 131072 fl
    ushort* Xt2  = (ushort*)(ws + 1604992);     // 6272*1984 sh = 6221824 fl
    float*  yb   = ws + 1604992;                // 61504 fl (alias: dead before Xt2 write)
    ushort* Xt3  = (ushort*)(ws + 1604992);     // 3072*1024 sh (alias: after gemm1)
    float*  p3   = ws + 7826816;                // 370176
    float*  z4   = ws + 8196992;                // 147200   (end 8344192 fl)
    float*  outp = (float*)d_out;

    k_sca_conv<<<dim3(64, 4), 256, 0, stream>>>(replay, ccw, ccb, yb);
    k_sca_fc<<<dim3(64, 50), 256, 0, stream>>>(yb, fcw, fcb, sca);
    k_wsum<<<964, 64, 0, stream>>>(w1, wsum);
    k_sa<<<dim3(4, 64), 256, 0, stream>>>(replay, w1, sa);
    k_whhT<<<157, 256, 0, stream>>>(whh, whhT);
    k_wbf<<<3968, 256, 0, stream>>>(w2, A2, 482, 1928, 512, 1984);
    k_wbf<<<1024, 256, 0, stream>>>(w3, A3, 241, 964, 256, 1024);
    k_cnn1<16, 1984><<<dim3(64, 62), 256, 0, stream>>>(sca, emb, w1, b1, wsum, sa, Xt2);
    // gemm1: N-tiles 49 (x), M-tiles 8 (y): launch 7*64=448 swizzled blocks
    k_gemm_conv<64, 128, 482, 98, 1984, true, 49, 8>
        <<<448, 256, 0, stream>>>(A2, Xt2, b2, p2b);
    k_im2col3<<<3072, 256, 0, stream>>>(p2b, Xt3);
    // gemm2: N-tiles 48, M-tiles 4: 6*32=192 blocks
    k_gemm_conv<64, 64, 241, 48, 1024, false, 48, 4>
        <<<192, 256, 0, stream>>>(A3, Xt3, b3, p3);
    k_conv<241, 100, 24><<<dim3(64, 4), 256, 0, stream>>>(p3, w4, b4, z4);
    k_fc_cnn<<<dim3(64, 25), 256, 0, stream>>>(z4, fcnw, fcnb, seq);
    k_xg<<<64, 512, 0, stream>>>(seq, wih, bih, bhh, xg);
    k_lstm<<<2, 512, 0, stream>>>(xg, whhT, fow, fob, outp);
}